// Round 1
// baseline (654.997 us; speedup 1.0000x reference)
//
#include <hip/hip_runtime.h>
#include <hip/hip_bf16.h>

// LinkClassifier: out[e] = relu(concat(h[s],h[t],ea,pooled[batch[s]]) @ W1 + b1) @ W2 + b2
// R5: T14 async-STAGE split in edge_kernel — prefetch next K-tile's gathers into
// registers during the MFMA phase, write to LDS after the post-compute barrier.
// K-tiles permuted so ea (f32->bf16 convert) is the prologue tile; all steady-state
// prefetches are bf16 uint4. build_wfrag matches the permutation.
// pool_kernel: uint4 loads + 2-deep unroll (breaks the 8B-serial latency chain).

typedef __attribute__((ext_vector_type(8))) short bf16x8;
typedef __attribute__((ext_vector_type(4))) float f32x4;

constexpr int kND = 256;
constexpr int kED = 128;
constexpr int kH  = 128;
constexpr int kKT = 7;     // K tiles of 128
constexpr int kB  = 2048;  // NUM_GRAPHS
constexpr int TM  = 128;   // edges per block
constexpr int SX  = 136;   // padded LDS row stride (bf16 elems)
constexpr int kNF = 224;   // W frag-sets: 28 ks * 2 nh * 4 ni

__device__ __forceinline__ ushort f2bf(float x) {
  union { float f; unsigned u; } c; c.f = x;
  unsigned u = c.u + 0x7FFFu + ((c.u >> 16) & 1u);
  return (ushort)(u >> 16);
}
__device__ __forceinline__ float bf2f(ushort x) {
  union { unsigned u; float f; } c; c.u = ((unsigned)x) << 16;
  return c.f;
}
__device__ __forceinline__ bool data_is_f32(const void* p) {
  const unsigned* u = (const unsigned*)p;
  int cnt = 0;
  #pragma unroll
  for (int i = 0; i < 64; ++i) {
    unsigned e = (u[i] >> 7) & 0xFFu;
    cnt += (e >= 90u && e <= 140u) ? 1 : 0;
  }
  return cnt < 40;
}
__device__ __forceinline__ bool idx_is_64(const int* __restrict__ p) {
  return ((p[1] | p[3] | p[5] | p[7]) == 0) && ((p[0] | p[2] | p[4] | p[6]) != 0);
}
__device__ __forceinline__ float loadf(const void* p, int i, bool isf32) {
  return isf32 ? ((const float*)p)[i] : bf2f(((const ushort*)p)[i]);
}

// ---------------- h (f32 or bf16) -> hbf (bf16), grid-stride ----------------
__global__ __launch_bounds__(256) void convert_h(
    const void* __restrict__ hv, ushort* __restrict__ hbf, long total4) {
  const bool isf32 = data_is_f32(hv);
  long i = (long)blockIdx.x * 256 + threadIdx.x;
  const long stride = (long)gridDim.x * 256;
  if (isf32) {
    const float4* src = (const float4*)hv;
    for (; i < total4; i += stride) {
      float4 f = src[i];
      ushort4 u; u.x = f2bf(f.x); u.y = f2bf(f.y); u.z = f2bf(f.z); u.w = f2bf(f.w);
      ((ushort4*)hbf)[i] = u;
    }
  } else {
    const ushort4* src = (const ushort4*)hv;
    for (; i < total4; i += stride) ((ushort4*)hbf)[i] = src[i];
  }
}

// ---------------- pooling: per-graph mean, 8 row-streams x 32 uint4 dim-groups ----------------
__global__ __launch_bounds__(256) void pool_kernel(
    const void* __restrict__ hv, const ushort* __restrict__ hbf, int preconv,
    const int* __restrict__ batch, const int* __restrict__ ei, int N,
    ushort* __restrict__ pooled) {
  const bool isf32 = data_is_f32(hv);
  const bool is64 = idx_is_64(ei);
  const int b = blockIdx.x, tid = threadIdx.x;
  __shared__ int bounds[2];
  __shared__ float sred[8][kND];
  if (tid < 2) {
    int target = b + tid;
    int lo = 0, hi = N;
    while (lo < hi) {
      int mid = (lo + hi) >> 1;
      int v = is64 ? batch[2 * mid] : batch[mid];
      if (v < target) lo = mid + 1; else hi = mid;
    }
    bounds[tid] = lo;
  }
  __syncthreads();
  const int lo = bounds[0], hi = bounds[1];
  const int dg = tid & 31;    // dims dg*8 .. dg*8+7
  const int rstr = tid >> 5;  // row stream 0..7
  float a[8];
  #pragma unroll
  for (int j = 0; j < 8; ++j) a[j] = 0.f;
  const ushort* hp = preconv ? hbf : (isf32 ? nullptr : (const ushort*)hv);
  if (hp) {
    const ushort* base = hp + dg * 8;
    int r = lo + rstr;
    for (; r + 8 < hi; r += 16) {
      union { uint4 v; ushort us[8]; } u0, u1;
      u0.v = *(const uint4*)(base + (size_t)r * kND);
      u1.v = *(const uint4*)(base + (size_t)(r + 8) * kND);
      #pragma unroll
      for (int j = 0; j < 8; ++j) a[j] += bf2f(u0.us[j]);
      #pragma unroll
      for (int j = 0; j < 8; ++j) a[j] += bf2f(u1.us[j]);
    }
    for (; r < hi; r += 8) {
      union { uint4 v; ushort us[8]; } u0;
      u0.v = *(const uint4*)(base + (size_t)r * kND);
      #pragma unroll
      for (int j = 0; j < 8; ++j) a[j] += bf2f(u0.us[j]);
    }
  } else {
    const float* base = (const float*)hv + dg * 8;
    int r = lo + rstr;
    for (; r + 8 < hi; r += 16) {
      float4 f0 = *(const float4*)(base + (size_t)r * kND);
      float4 f1 = *(const float4*)(base + (size_t)r * kND + 4);
      float4 f2 = *(const float4*)(base + (size_t)(r + 8) * kND);
      float4 f3 = *(const float4*)(base + (size_t)(r + 8) * kND + 4);
      a[0] += f0.x + f2.x; a[1] += f0.y + f2.y;
      a[2] += f0.z + f2.z; a[3] += f0.w + f2.w;
      a[4] += f1.x + f3.x; a[5] += f1.y + f3.y;
      a[6] += f1.z + f3.z; a[7] += f1.w + f3.w;
    }
    for (; r < hi; r += 8) {
      float4 f0 = *(const float4*)(base + (size_t)r * kND);
      float4 f1 = *(const float4*)(base + (size_t)r * kND + 4);
      a[0] += f0.x; a[1] += f0.y; a[2] += f0.z; a[3] += f0.w;
      a[4] += f1.x; a[5] += f1.y; a[6] += f1.z; a[7] += f1.w;
    }
  }
  #pragma unroll
  for (int j = 0; j < 8; ++j) sred[rstr][dg * 8 + j] = a[j];
  __syncthreads();
  // final: thread tid owns output dim tid; sum the 8 row-streams
  int cnt = hi - lo; if (cnt < 1) cnt = 1;
  float inv = 1.f / (float)cnt;
  float s = 0.f;
  #pragma unroll
  for (int st = 0; st < 8; ++st) s += sred[st][tid];
  pooled[(size_t)b * kND + tid] = f2bf(s * inv);
}

// ---------------- W1 [896][128] -> Wfrag: per-wave B-fragment order ----------------
// K-tile permutation (matches edge_kernel): tile 0 = ea (W1 rows 512..639),
// tiles 1,2 = h[s] (rows 0..255), tiles 3,4 = h[t] (rows 256..511),
// tiles 5,6 = pooled (rows 640..895).
__global__ __launch_bounds__(256) void build_wfrag(
    const void* __restrict__ W1v, ushort* __restrict__ Wfrag) {
  const bool isf32 = data_is_f32(W1v);
  int idx = blockIdx.x * 256 + threadIdx.x;
  if (idx >= kNF * 64) return;
  int l = idx & 63, f = idx >> 6;
  int ni = f & 3, nhi = (f >> 2) & 1, ksg = f >> 3;  // ksg 0..27
  int tile = ksg >> 2;
  int basek = (tile == 0) ? 512 : ((tile < 5) ? (tile - 1) * 128 : tile * 128);
  int n = nhi * 64 + ni * 16 + (l & 15);
  int k0 = basek + (ksg & 3) * 32 + (l >> 4) * 8;
  union { ushort us[8]; uint4 v; } cv;
  #pragma unroll
  for (int j = 0; j < 8; ++j)
    cv.us[j] = f2bf(loadf(W1v, (k0 + j) * kH + n, isf32));
  *(uint4*)(Wfrag + (size_t)f * 512 + l * 8) = cv.v;
}

// ---------------- fused edge MLP: gather + GEMM(MFMA) + relu + dot(W2) ----------------
// T14 schedule (hp path): prologue stages ea tile; per kt, prefetch tile kt+1 into
// regs BEFORE compute, drain at the post-compute barrier, write regs->LDS, barrier.
__global__ __launch_bounds__(256, 3) void edge_kernel(
    const void* __restrict__ hv, const ushort* __restrict__ hbf, int preconv,
    const int* __restrict__ ei, const void* __restrict__ eav,
    const int* __restrict__ batch, const ushort* __restrict__ pooled,
    const ushort* __restrict__ Wfrag, const void* __restrict__ b1v,
    const void* __restrict__ W2v, const void* __restrict__ b2v,
    void* __restrict__ outv, int E) {
  __shared__ __align__(16) ushort Xl[TM * SX];  // 34816 B
  __shared__ int rs[TM], rt[TM], rg[TM];
  __shared__ float outacc[TM];
  __shared__ float b1s[kH], w2s[kH];

  const int tid = threadIdx.x;
  const int e0 = blockIdx.x * TM;
  const bool isf32 = data_is_f32(hv);
  const bool is64 = idx_is_64(ei);

  if (tid < TM) {
    int e = e0 + tid; if (e >= E) e = E - 1;
    int s = is64 ? ei[2 * e] : ei[e];
    int t = is64 ? ei[2 * (E + e)] : ei[E + e];
    rs[tid] = s;
    rt[tid] = t;
    rg[tid] = is64 ? batch[2 * s] : batch[s];
    w2s[tid] = loadf(W2v, tid, isf32);
    b1s[tid] = loadf(b1v, tid, isf32);
    outacc[tid] = 0.f;
  }
  __syncthreads();

  const int wave = tid >> 6, lane = tid & 63;
  const int l15 = lane & 15, quad = lane >> 4;
  const int mh = (wave & 1) * 64;     // edge-half for this wave
  const int nhi = wave >> 1;          // hidden-half index
  const int nh = nhi * 64;

  f32x4 acc[4][4];
  #pragma unroll
  for (int i = 0; i < 4; ++i)
    #pragma unroll
    for (int j = 0; j < 4; ++j)
      acc[i][j] = (f32x4){0.f, 0.f, 0.f, 0.f};

  const int r0 = tid >> 4;
  const int c8 = (tid & 15) * 8;
  const ushort* hp = preconv ? hbf : (isf32 ? nullptr : (const ushort*)hv);

  // tile t meaning (K-perm, matched by build_wfrag):
  //   t=0: ea | t=1,2: h[s] halves | t=3,4: h[t] halves | t=5,6: pooled halves

  auto stage_ea = [&]() {
    #pragma unroll
    for (int i = 0; i < 8; ++i) {
      int r = r0 + i * 16;
      int e = e0 + r; if (e >= E) e = E - 1;
      uint4 val;
      if (isf32) {
        const float* s = (const float*)eav + (size_t)e * kED + c8;
        float4 f0 = ((const float4*)s)[0];
        float4 f1 = ((const float4*)s)[1];
        union { ushort us[8]; uint4 v; } cv;
        cv.us[0] = f2bf(f0.x); cv.us[1] = f2bf(f0.y);
        cv.us[2] = f2bf(f0.z); cv.us[3] = f2bf(f0.w);
        cv.us[4] = f2bf(f1.x); cv.us[5] = f2bf(f1.y);
        cv.us[6] = f2bf(f1.z); cv.us[7] = f2bf(f1.w);
        val = cv.v;
      } else {
        val = *(const uint4*)((const ushort*)eav + (size_t)e * kED + c8);
      }
      *(uint4*)&Xl[r * SX + c8] = val;
    }
  };

  auto compute_tile = [&](int kt) {
    #pragma unroll
    for (int ks = 0; ks < 4; ++ks) {
      const ushort* wp =
          Wfrag + ((size_t)(((kt * 4 + ks) * 2 + nhi) * 4)) * 512 + lane * 8;
      bf16x8 af[4], bfm[4];
      #pragma unroll
      for (int ni = 0; ni < 4; ++ni)
        bfm[ni] = *(const bf16x8*)(wp + ni * 512);
      int kk = ks * 32 + quad * 8;
      #pragma unroll
      for (int mi = 0; mi < 4; ++mi)
        af[mi] = *(const bf16x8*)&Xl[(mh + mi * 16 + l15) * SX + kk];
      #pragma unroll
      for (int mi = 0; mi < 4; ++mi)
        #pragma unroll
        for (int ni = 0; ni < 4; ++ni)
          acc[mi][ni] = __builtin_amdgcn_mfma_f32_16x16x32_bf16(
              af[mi], bfm[ni], acc[mi][ni], 0, 0, 0);
    }
  };

  if (hp) {
    // ---- T14 prefetch path: all steady-state tiles are bf16 uint4 gathers ----
    uint4 pre[8];
    stage_ea();
    __syncthreads();
    for (int kt = 0; kt < kKT; ++kt) {
      const int t = kt + 1;
      if (t < kKT) {
        if (t >= 5) {
          const size_t half = (size_t)(t - 5) * 128 + c8;
          #pragma unroll
          for (int i = 0; i < 8; ++i)
            pre[i] = *(const uint4*)(pooled + (size_t)rg[r0 + i * 16] * kND + half);
        } else {
          const size_t half = (size_t)((t - 1) & 1) * 128 + c8;
          const int* nn = (t < 3) ? rs : rt;
          #pragma unroll
          for (int i = 0; i < 8; ++i)
            pre[i] = *(const uint4*)(hp + (size_t)nn[r0 + i * 16] * kND + half);
        }
      }
      compute_tile(kt);
      __syncthreads();   // all waves done reading Xl; prefetch loads drain here
      if (t < kKT) {
        #pragma unroll
        for (int i = 0; i < 8; ++i)
          *(uint4*)&Xl[(r0 + i * 16) * SX + c8] = pre[i];
      }
      __syncthreads();
    }
  } else {
    // ---- fallback (h is f32, no workspace): in-place staging, permuted order ----
    for (int kt = 0; kt < kKT; ++kt) {
      if (kt == 0) {
        stage_ea();
      } else {
        #pragma unroll
        for (int i = 0; i < 8; ++i) {
          int r = r0 + i * 16;
          uint4 val;
          if (kt >= 5) {
            val = *(const uint4*)&pooled[(size_t)rg[r] * kND + (kt - 5) * 128 + c8];
          } else {
            int node = (kt < 3) ? rs[r] : rt[r];
            size_t off = (size_t)node * kND + ((kt - 1) & 1) * 128 + c8;
            const float* s = (const float*)hv + off;
            float4 f0 = ((const float4*)s)[0];
            float4 f1 = ((const float4*)s)[1];
            union { ushort us[8]; uint4 v; } cv;
            cv.us[0] = f2bf(f0.x); cv.us[1] = f2bf(f0.y);
            cv.us[2] = f2bf(f0.z); cv.us[3] = f2bf(f0.w);
            cv.us[4] = f2bf(f1.x); cv.us[5] = f2bf(f1.y);
            cv.us[6] = f2bf(f1.z); cv.us[7] = f2bf(f1.w);
            val = cv.v;
          }
          *(uint4*)&Xl[r * SX + c8] = val;
        }
      }
      __syncthreads();
      compute_tile(kt);
      __syncthreads();
    }
  }

  // ---- epilogue: sum_n relu(hid + b1) * W2 via shfl over the 16 n-lanes ----
  // C/D layout: col n = lane&15, row m = quad*4 + reg
  float w2v[4], b1r[4];
  #pragma unroll
  for (int ni = 0; ni < 4; ++ni) {
    int n = nh + ni * 16 + l15;
    w2v[ni] = w2s[n];
    b1r[ni] = b1s[n];
  }
  #pragma unroll
  for (int mi = 0; mi < 4; ++mi) {
    float ps[4] = {0.f, 0.f, 0.f, 0.f};
    #pragma unroll
    for (int ni = 0; ni < 4; ++ni)
      #pragma unroll
      for (int j = 0; j < 4; ++j) {
        float v = acc[mi][ni][j] + b1r[ni];
        ps[j] += (v > 0.f ? v : 0.f) * w2v[ni];
      }
    #pragma unroll
    for (int off = 1; off < 16; off <<= 1)
      #pragma unroll
      for (int j = 0; j < 4; ++j)
        ps[j] += __shfl_xor(ps[j], off, 64);
    if (l15 == 0)
      #pragma unroll
      for (int j = 0; j < 4; ++j)
        atomicAdd(&outacc[mh + mi * 16 + quad * 4 + j], ps[j]);
  }
  __syncthreads();
  if (tid < TM) {
    int e = e0 + tid;
    if (e < E) {
      float a = outacc[tid] + loadf(b2v, 0, isf32);
      if (isf32) ((float*)outv)[e] = a;
      else       ((ushort*)outv)[e] = f2bf(a);
    }
  }
}

extern "C" void kernel_launch(void* const* d_in, const int* in_sizes, int n_in,
                              void* d_out, int out_size, void* d_ws, size_t ws_size,
                              hipStream_t stream) {
  const void* h   = d_in[0];
  const int*  ei  = (const int*)d_in[1];
  const void* ea  = d_in[2];
  const int*  bat = (const int*)d_in[3];
  const void* W1  = d_in[4];
  const void* b1  = d_in[5];
  const void* W2  = d_in[6];
  const void* b2  = d_in[7];

  const int N = in_sizes[3];
  const int E = in_sizes[1] / 2;

  // ws layout: pooled bf16 [2048][256] | Wfrag bf16 [224*64*8] | hbf bf16 [N][256]
  ushort* pooled = (ushort*)d_ws;
  ushort* Wfrag  = pooled + (size_t)kB * kND;
  ushort* hbf    = Wfrag + (size_t)kNF * 512;
  const size_t need =
      ((size_t)kB * kND + (size_t)kNF * 512 + (size_t)N * kND) * sizeof(ushort);
  const int preconv = (ws_size >= need) ? 1 : 0;

  if (preconv)
    convert_h<<<4096, 256, 0, stream>>>(h, hbf, (long)N * kND / 4);
  pool_kernel<<<kB, 256, 0, stream>>>(h, hbf, preconv, bat, ei, N, pooled);
  build_wfrag<<<(kNF * 64 + 255) / 256, 256, 0, stream>>>(W1, Wfrag);
  edge_kernel<<<(E + TM - 1) / TM, 256, 0, stream>>>(
      h, hbf, preconv, ei, ea, bat, pooled, Wfrag, b1, W2, b2, d_out, E);
}

// Round 2
// 573.836 us; speedup vs baseline: 1.1414x; 1.1414x over previous
//
#include <hip/hip_runtime.h>
#include <hip/hip_bf16.h>

// LinkClassifier: out[e] = relu(concat(h[s],h[t],ea,pooled[batch[s]]) @ W1 + b1) @ W2 + b2
// R6: barrier-free direct-gather MFMA edge kernel. Per-lane 16B gathers ARE the
// A-fragments (lane l15 = row, quad = k-chunk) -> no LDS X tile, no K-loop barriers,
// no register prefetch held across MFMA (R5's spill bug). W streams from L2-resident
// Wfrag with compile-time offsets. convert_h folded into pool_kernel (writes hbf as
// a side effect of the one full read of h); h-bf16 case reads hv directly.

typedef __attribute__((ext_vector_type(8))) short bf16x8;
typedef __attribute__((ext_vector_type(4))) float f32x4;

constexpr int kND = 256;
constexpr int kED = 128;
constexpr int kH  = 128;
constexpr int kIN = 896;
constexpr int kKT = 7;     // K tiles of 128 (permuted: ea, hs, hs, ht, ht, g, g)
constexpr int kB  = 2048;  // NUM_GRAPHS
constexpr int TM  = 128;   // edges per block
constexpr int kNF = 224;   // W frag-sets: 28 ks * 2 nh * 4 ni

__device__ __forceinline__ ushort f2bf(float x) {
  union { float f; unsigned u; } c; c.f = x;
  unsigned u = c.u + 0x7FFFu + ((c.u >> 16) & 1u);
  return (ushort)(u >> 16);
}
__device__ __forceinline__ float bf2f(ushort x) {
  union { unsigned u; float f; } c; c.u = ((unsigned)x) << 16;
  return c.f;
}
__device__ __forceinline__ bool data_is_f32(const void* p) {
  const unsigned* u = (const unsigned*)p;
  int cnt = 0;
  #pragma unroll
  for (int i = 0; i < 64; ++i) {
    unsigned e = (u[i] >> 7) & 0xFFu;
    cnt += (e >= 90u && e <= 140u) ? 1 : 0;
  }
  return cnt < 40;
}
__device__ __forceinline__ bool idx_is_64(const int* __restrict__ p) {
  return ((p[1] | p[3] | p[5] | p[7]) == 0) && ((p[0] | p[2] | p[4] | p[6]) != 0);
}
__device__ __forceinline__ float loadf(const void* p, int i, bool isf32) {
  return isf32 ? ((const float*)p)[i] : bf2f(((const ushort*)p)[i]);
}
// 8 contiguous f32 -> bf16x8
__device__ __forceinline__ bf16x8 cvt8(const float* p) {
  float4 f0 = ((const float4*)p)[0];
  float4 f1 = ((const float4*)p)[1];
  union { ushort us[8]; bf16x8 v; } cv;
  cv.us[0] = f2bf(f0.x); cv.us[1] = f2bf(f0.y);
  cv.us[2] = f2bf(f0.z); cv.us[3] = f2bf(f0.w);
  cv.us[4] = f2bf(f1.x); cv.us[5] = f2bf(f1.y);
  cv.us[6] = f2bf(f1.z); cv.us[7] = f2bf(f1.w);
  return cv.v;
}

// ---------------- pooling: per-graph mean; also converts h->hbf when h is f32 ----------------
__global__ __launch_bounds__(256) void pool_kernel(
    const void* __restrict__ hv, ushort* __restrict__ hbf, int preconv,
    const int* __restrict__ batch, const int* __restrict__ ei, int N,
    ushort* __restrict__ pooled) {
  const bool isf32 = data_is_f32(hv);
  const bool is64 = idx_is_64(ei);
  const int b = blockIdx.x, tid = threadIdx.x;
  __shared__ int bounds[2];
  __shared__ float sred[8][kND];
  if (tid < 2) {
    int target = b + tid;
    int lo = 0, hi = N;
    while (lo < hi) {
      int mid = (lo + hi) >> 1;
      int v = is64 ? batch[2 * mid] : batch[mid];
      if (v < target) lo = mid + 1; else hi = mid;
    }
    bounds[tid] = lo;
  }
  __syncthreads();
  const int lo = bounds[0], hi = bounds[1];
  const int dg = tid & 31;    // dims dg*8 .. dg*8+7
  const int rstr = tid >> 5;  // row stream 0..7
  float a[8];
  #pragma unroll
  for (int j = 0; j < 8; ++j) a[j] = 0.f;

  if (!isf32) {
    // h already bf16: read hv directly, no copy
    const ushort* base = (const ushort*)hv + dg * 8;
    int r = lo + rstr;
    for (; r + 8 < hi; r += 16) {
      union { uint4 v; ushort us[8]; } u0, u1;
      u0.v = *(const uint4*)(base + (size_t)r * kND);
      u1.v = *(const uint4*)(base + (size_t)(r + 8) * kND);
      #pragma unroll
      for (int j = 0; j < 8; ++j) a[j] += bf2f(u0.us[j]);
      #pragma unroll
      for (int j = 0; j < 8; ++j) a[j] += bf2f(u1.us[j]);
    }
    for (; r < hi; r += 8) {
      union { uint4 v; ushort us[8]; } u0;
      u0.v = *(const uint4*)(base + (size_t)r * kND);
      #pragma unroll
      for (int j = 0; j < 8; ++j) a[j] += bf2f(u0.us[j]);
    }
  } else if (preconv) {
    // f32 h: accumulate AND write converted bf16 rows (replaces convert_h kernel)
    const float* base = (const float*)hv + dg * 8;
    ushort* wb = hbf + dg * 8;
    for (int r = lo + rstr; r < hi; r += 8) {
      float4 f0 = *(const float4*)(base + (size_t)r * kND);
      float4 f1 = *(const float4*)(base + (size_t)r * kND + 4);
      union { ushort us[8]; uint4 v; } cv;
      cv.us[0] = f2bf(f0.x); cv.us[1] = f2bf(f0.y);
      cv.us[2] = f2bf(f0.z); cv.us[3] = f2bf(f0.w);
      cv.us[4] = f2bf(f1.x); cv.us[5] = f2bf(f1.y);
      cv.us[6] = f2bf(f1.z); cv.us[7] = f2bf(f1.w);
      *(uint4*)(wb + (size_t)r * kND) = cv.v;
      a[0] += f0.x; a[1] += f0.y; a[2] += f0.z; a[3] += f0.w;
      a[4] += f1.x; a[5] += f1.y; a[6] += f1.z; a[7] += f1.w;
    }
  } else {
    const float* base = (const float*)hv + dg * 8;
    for (int r = lo + rstr; r < hi; r += 8) {
      float4 f0 = *(const float4*)(base + (size_t)r * kND);
      float4 f1 = *(const float4*)(base + (size_t)r * kND + 4);
      a[0] += f0.x; a[1] += f0.y; a[2] += f0.z; a[3] += f0.w;
      a[4] += f1.x; a[5] += f1.y; a[6] += f1.z; a[7] += f1.w;
    }
  }
  #pragma unroll
  for (int j = 0; j < 8; ++j) sred[rstr][dg * 8 + j] = a[j];
  __syncthreads();
  int cnt = hi - lo; if (cnt < 1) cnt = 1;
  float inv = 1.f / (float)cnt;
  float s = 0.f;
  #pragma unroll
  for (int st = 0; st < 8; ++st) s += sred[st][tid];
  pooled[(size_t)b * kND + tid] = f2bf(s * inv);
}

// ---------------- W1 [896][128] -> Wfrag: per-wave B-fragment order ----------------
// K-tile permutation: tile 0 = ea (W1 rows 512..639), tiles 1,2 = h[s] (rows 0..255),
// tiles 3,4 = h[t] (rows 256..511), tiles 5,6 = pooled (rows 640..895).
__global__ __launch_bounds__(256) void build_wfrag(
    const void* __restrict__ W1v, ushort* __restrict__ Wfrag) {
  const bool isf32 = data_is_f32(W1v);
  int idx = blockIdx.x * 256 + threadIdx.x;
  if (idx >= kNF * 64) return;
  int l = idx & 63, f = idx >> 6;
  int ni = f & 3, nhi = (f >> 2) & 1, ksg = f >> 3;  // ksg 0..27
  int tile = ksg >> 2;
  int basek = (tile == 0) ? 512 : ((tile < 5) ? (tile - 1) * 128 : tile * 128);
  int n = nhi * 64 + ni * 16 + (l & 15);
  int k0 = basek + (ksg & 3) * 32 + (l >> 4) * 8;
  union { ushort us[8]; uint4 v; } cv;
  #pragma unroll
  for (int j = 0; j < 8; ++j)
    cv.us[j] = f2bf(loadf(W1v, (k0 + j) * kH + n, isf32));
  *(uint4*)(Wfrag + (size_t)f * 512 + l * 8) = cv.v;
}

// ---------------- fused edge MLP: barrier-free direct-gather MFMA ----------------
// A-fragment for mfma_16x16x32: lane (l15,quad) holds row (mh+mi*16+l15),
// k = ks*32 + quad*8 .. +7 -> one 16B gather load per fragment, straight from global.
__global__ __launch_bounds__(256, 3) void edge_kernel(
    const void* __restrict__ hv, const ushort* __restrict__ hbf, int preconv,
    const int* __restrict__ ei, const void* __restrict__ eav,
    const int* __restrict__ batch, const ushort* __restrict__ pooled,
    const ushort* __restrict__ Wfrag, const void* __restrict__ b1v,
    const void* __restrict__ W2v, const void* __restrict__ b2v,
    void* __restrict__ outv, int E) {
  __shared__ int rs[TM], rt[TM], rg[TM];
  __shared__ float outacc[TM];
  __shared__ float b1s[kH], w2s[kH];

  const int tid = threadIdx.x;
  const int e0 = blockIdx.x * TM;
  const bool isf32 = data_is_f32(hv);
  const bool is64 = idx_is_64(ei);

  if (tid < TM) {
    int e = e0 + tid; if (e >= E) e = E - 1;
    int s = is64 ? ei[2 * e] : ei[e];
    int t = is64 ? ei[2 * (E + e)] : ei[E + e];
    rs[tid] = s;
    rt[tid] = t;
    rg[tid] = is64 ? batch[2 * s] : batch[s];
    w2s[tid] = loadf(W2v, tid, isf32);
    b1s[tid] = loadf(b1v, tid, isf32);
    outacc[tid] = 0.f;
  }
  __syncthreads();

  const int wave = tid >> 6, lane = tid & 63;
  const int l15 = lane & 15, quad = lane >> 4;
  const int mh = (wave & 1) * 64;     // edge-half for this wave
  const int nhi = wave >> 1;          // hidden-half index
  const int nh = nhi * 64;

  // h source: bf16 in hv directly, or converted hbf, or (fallback) f32 in hv
  const ushort* hp = isf32 ? (preconv ? hbf : nullptr) : (const ushort*)hv;
  const bool hb = (hp != nullptr);
  const bool ea32 = data_is_f32(eav);

  // per-lane gather base pointers (quad k-offset folded in)
  const char* bS[4]; const char* bT[4]; const ushort* bG[4]; const char* bE[4];
  #pragma unroll
  for (int mi = 0; mi < 4; ++mi) {
    int r = mh + mi * 16 + l15;
    int e = e0 + r; if (e >= E) e = E - 1;
    if (hb) {
      bS[mi] = (const char*)(hp + (size_t)rs[r] * kND + quad * 8);
      bT[mi] = (const char*)(hp + (size_t)rt[r] * kND + quad * 8);
    } else {
      bS[mi] = (const char*)((const float*)hv + (size_t)rs[r] * kND + quad * 8);
      bT[mi] = (const char*)((const float*)hv + (size_t)rt[r] * kND + quad * 8);
    }
    bG[mi] = pooled + (size_t)rg[r] * kND + quad * 8;
    bE[mi] = ea32 ? (const char*)((const float*)eav + (size_t)e * kED + quad * 8)
                  : (const char*)((const ushort*)eav + (size_t)e * kED + quad * 8);
  }

  f32x4 acc[4][4];
  #pragma unroll
  for (int i = 0; i < 4; ++i)
    #pragma unroll
    for (int j = 0; j < 4; ++j)
      acc[i][j] = (f32x4){0.f, 0.f, 0.f, 0.f};

  const ushort* wl = Wfrag + (size_t)nhi * 2048 + lane * 8;  // + ksg*4096 + ni*512

  #pragma unroll
  for (int kt = 0; kt < kKT; ++kt) {
    #pragma unroll
    for (int ks = 0; ks < 4; ++ks) {
      const int ksg = kt * 4 + ks;
      bf16x8 bfm[4];
      #pragma unroll
      for (int ni = 0; ni < 4; ++ni)
        bfm[ni] = *(const bf16x8*)(wl + (size_t)ksg * 4096 + ni * 512);
      bf16x8 af[4];
      #pragma unroll
      for (int mi = 0; mi < 4; ++mi) {
        if (kt == 0) {
          af[mi] = ea32 ? cvt8((const float*)bE[mi] + ks * 32)
                        : *(const bf16x8*)((const ushort*)bE[mi] + ks * 32);
        } else if (kt < 3) {
          af[mi] = hb ? *(const bf16x8*)(bS[mi] + (kt - 1) * 256 + ks * 64)
                      : cvt8((const float*)(bS[mi] + (size_t)(kt - 1) * 512 + ks * 128));
        } else if (kt < 5) {
          af[mi] = hb ? *(const bf16x8*)(bT[mi] + (kt - 3) * 256 + ks * 64)
                      : cvt8((const float*)(bT[mi] + (size_t)(kt - 3) * 512 + ks * 128));
        } else {
          af[mi] = *(const bf16x8*)(bG[mi] + (kt - 5) * 128 + ks * 32);
        }
      }
      #pragma unroll
      for (int mi = 0; mi < 4; ++mi)
        #pragma unroll
        for (int ni = 0; ni < 4; ++ni)
          acc[mi][ni] = __builtin_amdgcn_mfma_f32_16x16x32_bf16(
              af[mi], bfm[ni], acc[mi][ni], 0, 0, 0);
    }
  }

  // ---- epilogue: sum_n relu(hid + b1) * W2 via shfl over the 16 n-lanes ----
  // C/D layout: col n = lane&15, row m = quad*4 + reg
  float w2v[4], b1r[4];
  #pragma unroll
  for (int ni = 0; ni < 4; ++ni) {
    int n = nh + ni * 16 + l15;
    w2v[ni] = w2s[n];
    b1r[ni] = b1s[n];
  }
  #pragma unroll
  for (int mi = 0; mi < 4; ++mi) {
    float ps[4] = {0.f, 0.f, 0.f, 0.f};
    #pragma unroll
    for (int ni = 0; ni < 4; ++ni)
      #pragma unroll
      for (int j = 0; j < 4; ++j) {
        float v = acc[mi][ni][j] + b1r[ni];
        ps[j] += (v > 0.f ? v : 0.f) * w2v[ni];
      }
    #pragma unroll
    for (int off = 1; off < 16; off <<= 1)
      #pragma unroll
      for (int j = 0; j < 4; ++j)
        ps[j] += __shfl_xor(ps[j], off, 64);
    if (l15 == 0)
      #pragma unroll
      for (int j = 0; j < 4; ++j)
        atomicAdd(&outacc[mh + mi * 16 + quad * 4 + j], ps[j]);
  }
  __syncthreads();
  if (tid < TM) {
    int e = e0 + tid;
    if (e < E) {
      float a = outacc[tid] + loadf(b2v, 0, isf32);
      if (isf32) ((float*)outv)[e] = a;
      else       ((ushort*)outv)[e] = f2bf(a);
    }
  }
}

extern "C" void kernel_launch(void* const* d_in, const int* in_sizes, int n_in,
                              void* d_out, int out_size, void* d_ws, size_t ws_size,
                              hipStream_t stream) {
  const void* h   = d_in[0];
  const int*  ei  = (const int*)d_in[1];
  const void* ea  = d_in[2];
  const int*  bat = (const int*)d_in[3];
  const void* W1  = d_in[4];
  const void* b1  = d_in[5];
  const void* W2  = d_in[6];
  const void* b2  = d_in[7];

  const int N = in_sizes[3];
  const int E = in_sizes[1] / 2;

  // ws layout: pooled bf16 [2048][256] | Wfrag bf16 [224*64*8] | hbf bf16 [N][256]
  ushort* pooled = (ushort*)d_ws;
  ushort* Wfrag  = pooled + (size_t)kB * kND;
  ushort* hbf    = Wfrag + (size_t)kNF * 512;
  const size_t need =
      ((size_t)kB * kND + (size_t)kNF * 512 + (size_t)N * kND) * sizeof(ushort);
  const int preconv = (ws_size >= need) ? 1 : 0;

  pool_kernel<<<kB, 256, 0, stream>>>(h, hbf, preconv, bat, ei, N, pooled);
  build_wfrag<<<(kNF * 64 + 255) / 256, 256, 0, stream>>>(W1, Wfrag);
  edge_kernel<<<(E + TM - 1) / TM, 256, 0, stream>>>(
      h, hbf, preconv, ei, ea, bat, pooled, Wfrag, b1, W2, b2, d_out, E);
}

// Round 4
// 499.400 us; speedup vs baseline: 1.3116x; 1.1491x over previous
//
#include <hip/hip_runtime.h>
#include <hip/hip_bf16.h>

// LinkClassifier: out[e] = relu(concat(h[s],h[t],ea,pooled[batch[s]]) @ W1 + b1) @ W2 + b2
// R8 = R7 hardened resubmit. 2-phase async pipeline in edge_kernel (T3-minimum):
//   - global_load_lds(16B) staging into linear double-buffered LDS X tile (2x32KB)
//   - XOR swizzle (row&7)<<4 applied on per-lane GLOBAL source + on LDS read (rule 21)
//   - stage(t+1) issued BEFORE compute(t); single vmcnt(0)+barrier per tile
//   - W B-fragments loaded to regs BEFORE stage issue (sched_barrier-pinned) so their
//     counted vmcnt waits keep the stage loads in flight (FIFO semantics)
//   - ea f32 staged as raw-f32 subtiles (256B/row, same geometry), cvt after LDS read
// Hardening vs R7: AS(3) LDS pointer derived directly from the __shared__ decl and
// passed typed into edge_core (no generic->AS3 cast buried in lambdas).

typedef __attribute__((ext_vector_type(8))) short bf16x8;
typedef __attribute__((ext_vector_type(4))) float f32x4;
typedef __attribute__((address_space(3))) char lds_char;
typedef __attribute__((address_space(1))) const void g_cvoid;

constexpr int kND = 256;
constexpr int kED = 128;
constexpr int kH  = 128;
constexpr int kB  = 2048;  // NUM_GRAPHS
constexpr int TM  = 128;   // edges per block
constexpr int kNF = 224;   // W frag-sets: 28 ksg * 2 nh * 4 ni

__device__ __forceinline__ void gl2lds16(const void* gsrc, lds_char* ldst) {
  __builtin_amdgcn_global_load_lds((g_cvoid*)gsrc,
                                   (__attribute__((address_space(3))) void*)ldst,
                                   16, 0, 0);
}

__device__ __forceinline__ ushort f2bf(float x) {
  union { float f; unsigned u; } c; c.f = x;
  unsigned u = c.u + 0x7FFFu + ((c.u >> 16) & 1u);
  return (ushort)(u >> 16);
}
__device__ __forceinline__ float bf2f(ushort x) {
  union { unsigned u; float f; } c; c.u = ((unsigned)x) << 16;
  return c.f;
}
__device__ __forceinline__ bool data_is_f32(const void* p) {
  const unsigned* u = (const unsigned*)p;
  int cnt = 0;
  #pragma unroll
  for (int i = 0; i < 64; ++i) {
    unsigned e = (u[i] >> 7) & 0xFFu;
    cnt += (e >= 90u && e <= 140u) ? 1 : 0;
  }
  return cnt < 40;
}
__device__ __forceinline__ bool idx_is_64(const int* __restrict__ p) {
  return ((p[1] | p[3] | p[5] | p[7]) == 0) && ((p[0] | p[2] | p[4] | p[6]) != 0);
}
__device__ __forceinline__ float loadf(const void* p, int i, bool isf32) {
  return isf32 ? ((const float*)p)[i] : bf2f(((const ushort*)p)[i]);
}

// ---------------- pooling: per-graph mean; converts h->hbf when h is f32 ----------------
__global__ __launch_bounds__(256) void pool_kernel(
    const void* __restrict__ hv, ushort* __restrict__ hbf, int preconv,
    const int* __restrict__ batch, const int* __restrict__ ei, int N,
    ushort* __restrict__ pooled) {
  const bool isf32 = data_is_f32(hv);
  const bool is64 = idx_is_64(ei);
  const int b = blockIdx.x, tid = threadIdx.x;
  __shared__ int bounds[2];
  __shared__ float sred[8][kND];
  if (tid < 2) {
    int target = b + tid;
    int lo = 0, hi = N;
    while (lo < hi) {
      int mid = (lo + hi) >> 1;
      int v = is64 ? batch[2 * mid] : batch[mid];
      if (v < target) lo = mid + 1; else hi = mid;
    }
    bounds[tid] = lo;
  }
  __syncthreads();
  const int lo = bounds[0], hi = bounds[1];
  const int dg = tid & 31;
  const int rstr = tid >> 5;
  float a[8];
  #pragma unroll
  for (int j = 0; j < 8; ++j) a[j] = 0.f;

  if (!isf32) {
    const ushort* base = (const ushort*)hv + dg * 8;
    int r = lo + rstr;
    for (; r + 8 < hi; r += 16) {
      union { uint4 v; ushort us[8]; } u0, u1;
      u0.v = *(const uint4*)(base + (size_t)r * kND);
      u1.v = *(const uint4*)(base + (size_t)(r + 8) * kND);
      #pragma unroll
      for (int j = 0; j < 8; ++j) a[j] += bf2f(u0.us[j]);
      #pragma unroll
      for (int j = 0; j < 8; ++j) a[j] += bf2f(u1.us[j]);
    }
    for (; r < hi; r += 8) {
      union { uint4 v; ushort us[8]; } u0;
      u0.v = *(const uint4*)(base + (size_t)r * kND);
      #pragma unroll
      for (int j = 0; j < 8; ++j) a[j] += bf2f(u0.us[j]);
    }
  } else if (preconv) {
    const float* base = (const float*)hv + dg * 8;
    ushort* wb = hbf + dg * 8;
    for (int r = lo + rstr; r < hi; r += 8) {
      float4 f0 = *(const float4*)(base + (size_t)r * kND);
      float4 f1 = *(const float4*)(base + (size_t)r * kND + 4);
      union { ushort us[8]; uint4 v; } cv;
      cv.us[0] = f2bf(f0.x); cv.us[1] = f2bf(f0.y);
      cv.us[2] = f2bf(f0.z); cv.us[3] = f2bf(f0.w);
      cv.us[4] = f2bf(f1.x); cv.us[5] = f2bf(f1.y);
      cv.us[6] = f2bf(f1.z); cv.us[7] = f2bf(f1.w);
      *(uint4*)(wb + (size_t)r * kND) = cv.v;
      a[0] += f0.x; a[1] += f0.y; a[2] += f0.z; a[3] += f0.w;
      a[4] += f1.x; a[5] += f1.y; a[6] += f1.z; a[7] += f1.w;
    }
  } else {
    const float* base = (const float*)hv + dg * 8;
    for (int r = lo + rstr; r < hi; r += 8) {
      float4 f0 = *(const float4*)(base + (size_t)r * kND);
      float4 f1 = *(const float4*)(base + (size_t)r * kND + 4);
      a[0] += f0.x; a[1] += f0.y; a[2] += f0.z; a[3] += f0.w;
      a[4] += f1.x; a[5] += f1.y; a[6] += f1.z; a[7] += f1.w;
    }
  }
  #pragma unroll
  for (int j = 0; j < 8; ++j) sred[rstr][dg * 8 + j] = a[j];
  __syncthreads();
  int cnt = hi - lo; if (cnt < 1) cnt = 1;
  float inv = 1.f / (float)cnt;
  float s = 0.f;
  #pragma unroll
  for (int st = 0; st < 8; ++st) s += sred[st][tid];
  pooled[(size_t)b * kND + tid] = f2bf(s * inv);
}

// ---------------- W1 [896][128] -> Wfrag: per-wave B-fragment order ----------------
// ksg (0..27) -> W1 rows: ea = ksg 0..3 (rows 512..639), h[s] = ksg 4..11 (rows 0..255),
// h[t] = ksg 12..19 (rows 256..511), pooled = ksg 20..27 (rows 640..895).
__global__ __launch_bounds__(256) void build_wfrag(
    const void* __restrict__ W1v, ushort* __restrict__ Wfrag) {
  const bool isf32 = data_is_f32(W1v);
  int idx = blockIdx.x * 256 + threadIdx.x;
  if (idx >= kNF * 64) return;
  int l = idx & 63, f = idx >> 6;
  int ni = f & 3, nhi = (f >> 2) & 1, ksg = f >> 3;
  int tile = ksg >> 2;
  int basek = (tile == 0) ? 512 : ((tile < 5) ? (tile - 1) * 128 : tile * 128);
  int n = nhi * 64 + ni * 16 + (l & 15);
  int k0 = basek + (ksg & 3) * 32 + (l >> 4) * 8;
  union { ushort us[8]; uint4 v; } cv;
  #pragma unroll
  for (int j = 0; j < 8; ++j)
    cv.us[j] = f2bf(loadf(W1v, (k0 + j) * kH + n, isf32));
  *(uint4*)(Wfrag + (size_t)f * 512 + l * 8) = cv.v;
}

// ---- tile descriptors: 256B/row sub-tiles covering the permuted K axis ----
// ty: 0=ea 1=h[s] 2=h[t] 3=pooled ; sub: 256B-subtile index ; ksc: ks-steps (32 k each)
template<bool HB, bool EA32> struct TD;
template<> struct TD<true, true> {   // h bf16, ea f32
  static constexpr int NT = 8;
  static constexpr int ty[8]  = {0,0,1,1,2,2,3,3};
  static constexpr int sub[8] = {0,1,0,1,0,1,0,1};
  static constexpr int ksc[8] = {2,2,4,4,4,4,4,4};
  static constexpr int kg0[8] = {0,2,4,8,12,16,20,24};
  static constexpr bool tf32[8] = {1,1,0,0,0,0,0,0};
};
template<> struct TD<true, false> {  // h bf16, ea bf16
  static constexpr int NT = 7;
  static constexpr int ty[7]  = {0,1,1,2,2,3,3};
  static constexpr int sub[7] = {0,0,1,0,1,0,1};
  static constexpr int ksc[7] = {4,4,4,4,4,4,4};
  static constexpr int kg0[7] = {0,4,8,12,16,20,24};
  static constexpr bool tf32[7] = {0,0,0,0,0,0,0};
};
template<> struct TD<false, true> {  // h f32 (raw), ea f32
  static constexpr int NT = 12;
  static constexpr int ty[12]  = {0,0,1,1,1,1,2,2,2,2,3,3};
  static constexpr int sub[12] = {0,1,0,1,2,3,0,1,2,3,0,1};
  static constexpr int ksc[12] = {2,2,2,2,2,2,2,2,2,2,4,4};
  static constexpr int kg0[12] = {0,2,4,6,8,10,12,14,16,18,20,24};
  static constexpr bool tf32[12] = {1,1,1,1,1,1,1,1,1,1,0,0};
};
template<> struct TD<false, false> { // h f32 (raw), ea bf16
  static constexpr int NT = 11;
  static constexpr int ty[11]  = {0,1,1,1,1,2,2,2,2,3,3};
  static constexpr int sub[11] = {0,0,1,2,3,0,1,2,3,0,1};
  static constexpr int ksc[11] = {4,2,2,2,2,2,2,2,2,4,4};
  static constexpr int kg0[11] = {0,4,6,8,10,12,14,16,18,20,24};
  static constexpr bool tf32[11] = {0,1,1,1,1,1,1,1,1,0,0};
};

template<bool HB, bool EA32>
__device__ __forceinline__ void edge_core(
    const char* __restrict__ hsrc, const char* __restrict__ easrc,
    const ushort* __restrict__ pooled, const ushort* __restrict__ Wfrag,
    const char* XlB, lds_char* Xl3, const int* rs, const int* rt, const int* rg,
    int e0, int E, int wave, int lane, f32x4 (&acc)[4][4]) {
  using T = TD<HB, EA32>;
  const int l15 = lane & 15, quad = lane >> 4;
  const int mh = (wave & 1) * 64;
  const int nhi = wave >> 1;
  const ushort* wl = Wfrag + (size_t)nhi * 2048 + lane * 8;
  const int cx0 = (lane & 15) * 16;
  const int rlane = lane >> 4;

  // per-lane swizzled global source for (tile, row): content X[row][cx0 ^ swz(row)]
  auto src_addr = [&](int t, int row) -> const char* {
    int cx = cx0 ^ ((row & 7) << 4);
    int ty = T::ty[t], sub = T::sub[t];
    if (ty == 0) {
      int e = e0 + row; if (e >= E) e = E - 1;
      return easrc + (size_t)e * (EA32 ? 512 : 256) + sub * 256 + cx;
    }
    if (ty == 1) return hsrc + (size_t)rs[row] * (HB ? 512 : 1024) + sub * 256 + cx;
    if (ty == 2) return hsrc + (size_t)rt[row] * (HB ? 512 : 1024) + sub * 256 + cx;
    return (const char*)pooled + (size_t)rg[row] * 512 + sub * 256 + cx;
  };
  // stage tile t into buf[t&1]: linear dest (wave-uniform base + lane*16), swizzled src
  auto stage = [&](int t) {
    lds_char* dst = Xl3 + (t & 1) * 32768;
    #pragma unroll
    for (int i = 0; i < 8; ++i) {
      int row = wave * 32 + i * 4 + rlane;
      gl2lds16(src_addr(t, row), dst + (wave * 32 + i * 4) * 256);
    }
  };

  stage(0);
  __syncthreads();   // compiler drains vmcnt here

  #pragma unroll
  for (int t = 0; t < T::NT; ++t) {
    // --- B-fragments for this tile: issued BEFORE stage so their counted
    //     vmcnt waits keep the stage loads in flight (FIFO) ---
    bf16x8 bq[16];
    #pragma unroll
    for (int ks = 0; ks < T::ksc[t]; ++ks)
      #pragma unroll
      for (int ni = 0; ni < 4; ++ni)
        bq[ks * 4 + ni] =
            *(const bf16x8*)(wl + (size_t)(T::kg0[t] + ks) * 4096 + ni * 512);
    __builtin_amdgcn_sched_barrier(0);  // pin: bq issue precedes stage issue
    if (t + 1 < T::NT) stage(t + 1);

    // --- compute tile t from buf[t&1] ---
    const char* xb = XlB + (t & 1) * 32768;
    #pragma unroll
    for (int ks = 0; ks < T::ksc[t]; ++ks) {
      bf16x8 af[4];
      #pragma unroll
      for (int mi = 0; mi < 4; ++mi) {
        int row = mh + mi * 16 + l15;
        int sz = (row & 7) << 4;
        const char* rb = xb + row * 256;
        if (T::tf32[t]) {
          int cb = ks * 128 + quad * 32;
          float4 f0 = *(const float4*)(rb + (cb ^ sz));
          float4 f1 = *(const float4*)(rb + ((cb + 16) ^ sz));
          union { ushort us[8]; bf16x8 v; } cv;
          cv.us[0] = f2bf(f0.x); cv.us[1] = f2bf(f0.y);
          cv.us[2] = f2bf(f0.z); cv.us[3] = f2bf(f0.w);
          cv.us[4] = f2bf(f1.x); cv.us[5] = f2bf(f1.y);
          cv.us[6] = f2bf(f1.z); cv.us[7] = f2bf(f1.w);
          af[mi] = cv.v;
        } else {
          int cb = ks * 64 + quad * 16;
          af[mi] = *(const bf16x8*)(rb + (cb ^ sz));
        }
      }
      #pragma unroll
      for (int mi = 0; mi < 4; ++mi)
        #pragma unroll
        for (int ni = 0; ni < 4; ++ni)
          acc[mi][ni] = __builtin_amdgcn_mfma_f32_16x16x32_bf16(
              af[mi], bq[ks * 4 + ni], acc[mi][ni], 0, 0, 0);
    }
    __syncthreads();  // drains stage(t+1) (vmcnt(0) auto) + buffer handoff
  }
}

// ---------------- fused edge MLP: pipelined gather + GEMM(MFMA) + relu + dot(W2) ----------------
__global__ __launch_bounds__(256, 2) void edge_kernel(
    const void* __restrict__ hv, const ushort* __restrict__ hbf, int preconv,
    const int* __restrict__ ei, const void* __restrict__ eav,
    const int* __restrict__ batch, const ushort* __restrict__ pooled,
    const ushort* __restrict__ Wfrag, const void* __restrict__ b1v,
    const void* __restrict__ W2v, const void* __restrict__ b2v,
    void* __restrict__ outv, int E) {
  __shared__ __align__(16) char XlB[2 * 32768];  // X double buffer, linear 256B rows
  __shared__ int rs[TM], rt[TM], rg[TM];
  __shared__ float outacc[TM];
  __shared__ float b1s[kH], w2s[kH];
  lds_char* Xl3 = (lds_char*)XlB;  // AS(3) view, derived at the declaration

  const int tid = threadIdx.x;
  const int e0 = blockIdx.x * TM;
  const bool isf32 = data_is_f32(hv);
  const bool is64 = idx_is_64(ei);

  if (tid < TM) {
    int e = e0 + tid; if (e >= E) e = E - 1;
    int s = is64 ? ei[2 * e] : ei[e];
    int t = is64 ? ei[2 * (E + e)] : ei[E + e];
    rs[tid] = s;
    rt[tid] = t;
    rg[tid] = is64 ? batch[2 * s] : batch[s];
    w2s[tid] = loadf(W2v, tid, isf32);
    b1s[tid] = loadf(b1v, tid, isf32);
    outacc[tid] = 0.f;
  }
  __syncthreads();

  const int wave = tid >> 6, lane = tid & 63;
  const int l15 = lane & 15, quad = lane >> 4;
  const int mh = (wave & 1) * 64;
  const int nhi = wave >> 1;
  const int nh = nhi * 64;

  f32x4 acc[4][4];
  #pragma unroll
  for (int i = 0; i < 4; ++i)
    #pragma unroll
    for (int j = 0; j < 4; ++j)
      acc[i][j] = (f32x4){0.f, 0.f, 0.f, 0.f};

  const bool hb = !isf32 || preconv;
  const char* hsrc = !isf32 ? (const char*)hv
                            : (preconv ? (const char*)hbf : (const char*)hv);
  const bool ea32 = data_is_f32(eav);

  if (hb) {
    if (ea32) edge_core<true, true >((const char*)hsrc, (const char*)eav, pooled,
                                     Wfrag, XlB, Xl3, rs, rt, rg, e0, E, wave, lane, acc);
    else      edge_core<true, false>((const char*)hsrc, (const char*)eav, pooled,
                                     Wfrag, XlB, Xl3, rs, rt, rg, e0, E, wave, lane, acc);
  } else {
    if (ea32) edge_core<false, true >((const char*)hsrc, (const char*)eav, pooled,
                                      Wfrag, XlB, Xl3, rs, rt, rg, e0, E, wave, lane, acc);
    else      edge_core<false, false>((const char*)hsrc, (const char*)eav, pooled,
                                      Wfrag, XlB, Xl3, rs, rt, rg, e0, E, wave, lane, acc);
  }

  // ---- epilogue: sum_n relu(hid + b1) * W2 via shfl over the 16 n-lanes ----
  // C/D layout: col n = lane&15, row m = quad*4 + reg
  float w2v[4], b1r[4];
  #pragma unroll
  for (int ni = 0; ni < 4; ++ni) {
    int n = nh + ni * 16 + l15;
    w2v[ni] = w2s[n];
    b1r[ni] = b1s[n];
  }
  #pragma unroll
  for (int mi = 0; mi < 4; ++mi) {
    float ps[4] = {0.f, 0.f, 0.f, 0.f};
    #pragma unroll
    for (int ni = 0; ni < 4; ++ni)
      #pragma unroll
      for (int j = 0; j < 4; ++j) {
        float v = acc[mi][ni][j] + b1r[ni];
        ps[j] += (v > 0.f ? v : 0.f) * w2v[ni];
      }
    #pragma unroll
    for (int off = 1; off < 16; off <<= 1)
      #pragma unroll
      for (int j = 0; j < 4; ++j)
        ps[j] += __shfl_xor(ps[j], off, 64);
    if (l15 == 0)
      #pragma unroll
      for (int j = 0; j < 4; ++j)
        atomicAdd(&outacc[mh + mi * 16 + quad * 4 + j], ps[j]);
  }
  __syncthreads();
  if (tid < TM) {
    int e = e0 + tid;
    if (e < E) {
      float a = outacc[tid] + loadf(b2v, 0, isf32);
      if (isf32) ((float*)outv)[e] = a;
      else       ((ushort*)outv)[e] = f2bf(a);
    }
  }
}

extern "C" void kernel_launch(void* const* d_in, const int* in_sizes, int n_in,
                              void* d_out, int out_size, void* d_ws, size_t ws_size,
                              hipStream_t stream) {
  const void* h   = d_in[0];
  const int*  ei  = (const int*)d_in[1];
  const void* ea  = d_in[2];
  const int*  bat = (const int*)d_in[3];
  const void* W1  = d_in[4];
  const void* b1  = d_in[5];
  const void* W2  = d_in[6];
  const void* b2  = d_in[7];

  const int N = in_sizes[3];
  const int E = in_sizes[1] / 2;

  // ws layout: pooled bf16 [2048][256] | Wfrag bf16 [224*64*8] | hbf bf16 [N][256]
  ushort* pooled = (ushort*)d_ws;
  ushort* Wfrag  = pooled + (size_t)kB * kND;
  ushort* hbf    = Wfrag + (size_t)kNF * 512;
  const size_t need =
      ((size_t)kB * kND + (size_t)kNF * 512 + (size_t)N * kND) * sizeof(ushort);
  const int preconv = (ws_size >= need) ? 1 : 0;

  pool_kernel<<<kB, 256, 0, stream>>>(h, hbf, preconv, bat, ei, N, pooled);
  build_wfrag<<<(kNF * 64 + 255) / 256, 256, 0, stream>>>(W1, Wfrag);
  edge_kernel<<<(E + TM - 1) / TM, 256, 0, stream>>>(
      h, hbf, preconv, ei, ea, bat, pooled, Wfrag, b1, W2, b2, d_out, E);
}

// Round 5
// 497.650 us; speedup vs baseline: 1.3162x; 1.0035x over previous
//
#include <hip/hip_runtime.h>
#include <hip/hip_bf16.h>

// LinkClassifier: out[e] = relu(concat(h[s],h[t],ea,pooled[batch[s]]) @ W1 + b1) @ W2 + b2
// R9 = R8 pipeline at 2x wave-parallelism. Same 128-edge x 128-col block, same
// 2-phase global_load_lds(16B) double-buffered staging with XOR-swizzled source +
// FIFO-ordered W-fragment loads -- but 8 waves (512 thr), each owning a 64x32 output
// slice (acc 4x2, bq 8). LDS unchanged (68.6KB, 2 blocks/CU) -> 16 waves/CU =
// 4 waves/SIMD (was 2): double the latency-hiding TLP at constant LDS.
// __launch_bounds__(512,4) caps VGPR at 128 (acc32+bq32+af16+addr ~= 115, no spill).

typedef __attribute__((ext_vector_type(8))) short bf16x8;
typedef __attribute__((ext_vector_type(4))) float f32x4;
typedef __attribute__((address_space(3))) char lds_char;
typedef __attribute__((address_space(1))) const void g_cvoid;

constexpr int kND = 256;
constexpr int kED = 128;
constexpr int kH  = 128;
constexpr int kB  = 2048;  // NUM_GRAPHS
constexpr int TM  = 128;   // edges per block
constexpr int kNF = 224;   // W frag-sets: 28 ksg * 2 nh * 4 ni

__device__ __forceinline__ void gl2lds16(const void* gsrc, lds_char* ldst) {
  __builtin_amdgcn_global_load_lds((g_cvoid*)gsrc,
                                   (__attribute__((address_space(3))) void*)ldst,
                                   16, 0, 0);
}

__device__ __forceinline__ ushort f2bf(float x) {
  union { float f; unsigned u; } c; c.f = x;
  unsigned u = c.u + 0x7FFFu + ((c.u >> 16) & 1u);
  return (ushort)(u >> 16);
}
__device__ __forceinline__ float bf2f(ushort x) {
  union { unsigned u; float f; } c; c.u = ((unsigned)x) << 16;
  return c.f;
}
__device__ __forceinline__ bool data_is_f32(const void* p) {
  const unsigned* u = (const unsigned*)p;
  int cnt = 0;
  #pragma unroll
  for (int i = 0; i < 64; ++i) {
    unsigned e = (u[i] >> 7) & 0xFFu;
    cnt += (e >= 90u && e <= 140u) ? 1 : 0;
  }
  return cnt < 40;
}
__device__ __forceinline__ bool idx_is_64(const int* __restrict__ p) {
  return ((p[1] | p[3] | p[5] | p[7]) == 0) && ((p[0] | p[2] | p[4] | p[6]) != 0);
}
__device__ __forceinline__ float loadf(const void* p, int i, bool isf32) {
  return isf32 ? ((const float*)p)[i] : bf2f(((const ushort*)p)[i]);
}

// ---------------- pooling: per-graph mean; converts h->hbf when h is f32 ----------------
__global__ __launch_bounds__(256) void pool_kernel(
    const void* __restrict__ hv, ushort* __restrict__ hbf, int preconv,
    const int* __restrict__ batch, const int* __restrict__ ei, int N,
    ushort* __restrict__ pooled) {
  const bool isf32 = data_is_f32(hv);
  const bool is64 = idx_is_64(ei);
  const int b = blockIdx.x, tid = threadIdx.x;
  __shared__ int bounds[2];
  __shared__ float sred[8][kND];
  if (tid < 2) {
    int target = b + tid;
    int lo = 0, hi = N;
    while (lo < hi) {
      int mid = (lo + hi) >> 1;
      int v = is64 ? batch[2 * mid] : batch[mid];
      if (v < target) lo = mid + 1; else hi = mid;
    }
    bounds[tid] = lo;
  }
  __syncthreads();
  const int lo = bounds[0], hi = bounds[1];
  const int dg = tid & 31;
  const int rstr = tid >> 5;
  float a[8];
  #pragma unroll
  for (int j = 0; j < 8; ++j) a[j] = 0.f;

  if (!isf32) {
    const ushort* base = (const ushort*)hv + dg * 8;
    int r = lo + rstr;
    for (; r + 8 < hi; r += 16) {
      union { uint4 v; ushort us[8]; } u0, u1;
      u0.v = *(const uint4*)(base + (size_t)r * kND);
      u1.v = *(const uint4*)(base + (size_t)(r + 8) * kND);
      #pragma unroll
      for (int j = 0; j < 8; ++j) a[j] += bf2f(u0.us[j]);
      #pragma unroll
      for (int j = 0; j < 8; ++j) a[j] += bf2f(u1.us[j]);
    }
    for (; r < hi; r += 8) {
      union { uint4 v; ushort us[8]; } u0;
      u0.v = *(const uint4*)(base + (size_t)r * kND);
      #pragma unroll
      for (int j = 0; j < 8; ++j) a[j] += bf2f(u0.us[j]);
    }
  } else if (preconv) {
    const float* base = (const float*)hv + dg * 8;
    ushort* wb = hbf + dg * 8;
    for (int r = lo + rstr; r < hi; r += 8) {
      float4 f0 = *(const float4*)(base + (size_t)r * kND);
      float4 f1 = *(const float4*)(base + (size_t)r * kND + 4);
      union { ushort us[8]; uint4 v; } cv;
      cv.us[0] = f2bf(f0.x); cv.us[1] = f2bf(f0.y);
      cv.us[2] = f2bf(f0.z); cv.us[3] = f2bf(f0.w);
      cv.us[4] = f2bf(f1.x); cv.us[5] = f2bf(f1.y);
      cv.us[6] = f2bf(f1.z); cv.us[7] = f2bf(f1.w);
      *(uint4*)(wb + (size_t)r * kND) = cv.v;
      a[0] += f0.x; a[1] += f0.y; a[2] += f0.z; a[3] += f0.w;
      a[4] += f1.x; a[5] += f1.y; a[6] += f1.z; a[7] += f1.w;
    }
  } else {
    const float* base = (const float*)hv + dg * 8;
    for (int r = lo + rstr; r < hi; r += 8) {
      float4 f0 = *(const float4*)(base + (size_t)r * kND);
      float4 f1 = *(const float4*)(base + (size_t)r * kND + 4);
      a[0] += f0.x; a[1] += f0.y; a[2] += f0.z; a[3] += f0.w;
      a[4] += f1.x; a[5] += f1.y; a[6] += f1.z; a[7] += f1.w;
    }
  }
  #pragma unroll
  for (int j = 0; j < 8; ++j) sred[rstr][dg * 8 + j] = a[j];
  __syncthreads();
  int cnt = hi - lo; if (cnt < 1) cnt = 1;
  float inv = 1.f / (float)cnt;
  float s = 0.f;
  #pragma unroll
  for (int st = 0; st < 8; ++st) s += sred[st][tid];
  pooled[(size_t)b * kND + tid] = f2bf(s * inv);
}

// ---------------- W1 [896][128] -> Wfrag: per-wave B-fragment order ----------------
// ksg (0..27) -> W1 rows: ea = ksg 0..3 (rows 512..639), h[s] = ksg 4..11 (rows 0..255),
// h[t] = ksg 12..19 (rows 256..511), pooled = ksg 20..27 (rows 640..895).
__global__ __launch_bounds__(256) void build_wfrag(
    const void* __restrict__ W1v, ushort* __restrict__ Wfrag) {
  const bool isf32 = data_is_f32(W1v);
  int idx = blockIdx.x * 256 + threadIdx.x;
  if (idx >= kNF * 64) return;
  int l = idx & 63, f = idx >> 6;
  int ni = f & 3, nhi = (f >> 2) & 1, ksg = f >> 3;
  int tile = ksg >> 2;
  int basek = (tile == 0) ? 512 : ((tile < 5) ? (tile - 1) * 128 : tile * 128);
  int n = nhi * 64 + ni * 16 + (l & 15);
  int k0 = basek + (ksg & 3) * 32 + (l >> 4) * 8;
  union { ushort us[8]; uint4 v; } cv;
  #pragma unroll
  for (int j = 0; j < 8; ++j)
    cv.us[j] = f2bf(loadf(W1v, (k0 + j) * kH + n, isf32));
  *(uint4*)(Wfrag + (size_t)f * 512 + l * 8) = cv.v;
}

// ---- tile descriptors: 256B/row sub-tiles covering the permuted K axis ----
// ty: 0=ea 1=h[s] 2=h[t] 3=pooled ; sub: 256B-subtile index ; ksc: ks-steps (32 k each)
template<bool HB, bool EA32> struct TD;
template<> struct TD<true, true> {   // h bf16, ea f32
  static constexpr int NT = 8;
  static constexpr int ty[8]  = {0,0,1,1,2,2,3,3};
  static constexpr int sub[8] = {0,1,0,1,0,1,0,1};
  static constexpr int ksc[8] = {2,2,4,4,4,4,4,4};
  static constexpr int kg0[8] = {0,2,4,8,12,16,20,24};
  static constexpr bool tf32[8] = {1,1,0,0,0,0,0,0};
};
template<> struct TD<true, false> {  // h bf16, ea bf16
  static constexpr int NT = 7;
  static constexpr int ty[7]  = {0,1,1,2,2,3,3};
  static constexpr int sub[7] = {0,0,1,0,1,0,1};
  static constexpr int ksc[7] = {4,4,4,4,4,4,4};
  static constexpr int kg0[7] = {0,4,8,12,16,20,24};
  static constexpr bool tf32[7] = {0,0,0,0,0,0,0};
};
template<> struct TD<false, true> {  // h f32 (raw), ea f32
  static constexpr int NT = 12;
  static constexpr int ty[12]  = {0,0,1,1,1,1,2,2,2,2,3,3};
  static constexpr int sub[12] = {0,1,0,1,2,3,0,1,2,3,0,1};
  static constexpr int ksc[12] = {2,2,2,2,2,2,2,2,2,2,4,4};
  static constexpr int kg0[12] = {0,2,4,6,8,10,12,14,16,18,20,24};
  static constexpr bool tf32[12] = {1,1,1,1,1,1,1,1,1,1,0,0};
};
template<> struct TD<false, false> { // h f32 (raw), ea bf16
  static constexpr int NT = 11;
  static constexpr int ty[11]  = {0,1,1,1,1,2,2,2,2,3,3};
  static constexpr int sub[11] = {0,0,1,2,3,0,1,2,3,0,1};
  static constexpr int ksc[11] = {4,2,2,2,2,2,2,2,2,4,4};
  static constexpr int kg0[11] = {0,4,6,8,10,12,14,16,18,20,24};
  static constexpr bool tf32[11] = {0,1,1,1,1,1,1,1,1,0,0};
};

template<bool HB, bool EA32>
__device__ __forceinline__ void edge_core(
    const char* __restrict__ hsrc, const char* __restrict__ easrc,
    const ushort* __restrict__ pooled, const ushort* __restrict__ Wfrag,
    const char* XlB, lds_char* Xl3, const int* rs, const int* rt, const int* rg,
    int e0, int E, int wave, int lane, f32x4 (&acc)[4][2]) {
  using T = TD<HB, EA32>;
  const int l15 = lane & 15, quad = lane >> 4;
  const int mh = (wave & 1) * 64;        // row half
  const int nq = wave >> 1;              // col slice 0..3 (32 cols each)
  const int nhi = nq >> 1;               // Wfrag n-half
  const int nlo = (nq & 1) * 2;          // abs ni base within half
  const ushort* wl = Wfrag + (size_t)nhi * 2048 + lane * 8;
  const int cx0 = (lane & 15) * 16;
  const int rlane = lane >> 4;

  // per-lane swizzled global source for (tile, row): content X[row][cx0 ^ swz(row)]
  auto src_addr = [&](int t, int row) -> const char* {
    int cx = cx0 ^ ((row & 7) << 4);
    int ty = T::ty[t], sub = T::sub[t];
    if (ty == 0) {
      int e = e0 + row; if (e >= E) e = E - 1;
      return easrc + (size_t)e * (EA32 ? 512 : 256) + sub * 256 + cx;
    }
    if (ty == 1) return hsrc + (size_t)rs[row] * (HB ? 512 : 1024) + sub * 256 + cx;
    if (ty == 2) return hsrc + (size_t)rt[row] * (HB ? 512 : 1024) + sub * 256 + cx;
    return (const char*)pooled + (size_t)rg[row] * 512 + sub * 256 + cx;
  };
  // stage tile t into buf[t&1]: 8 waves x 4 iters x 64 lanes = 128 rows x 256B
  auto stage = [&](int t) {
    lds_char* dst = Xl3 + (t & 1) * 32768;
    #pragma unroll
    for (int i = 0; i < 4; ++i) {
      int row = wave * 16 + i * 4 + rlane;
      gl2lds16(src_addr(t, row), dst + (wave * 16 + i * 4) * 256);
    }
  };

  stage(0);
  __syncthreads();   // compiler drains vmcnt here

  #pragma unroll
  for (int t = 0; t < T::NT; ++t) {
    // --- B-fragments for this tile: issued BEFORE stage so their counted
    //     vmcnt waits keep the stage loads in flight (FIFO) ---
    bf16x8 bq[8];
    #pragma unroll
    for (int ks = 0; ks < T::ksc[t]; ++ks)
      #pragma unroll
      for (int ni = 0; ni < 2; ++ni)
        bq[ks * 2 + ni] =
            *(const bf16x8*)(wl + (size_t)(T::kg0[t] + ks) * 4096 + (nlo + ni) * 512);
    __builtin_amdgcn_sched_barrier(0);  // pin: bq issue precedes stage issue
    if (t + 1 < T::NT) stage(t + 1);

    // --- compute tile t from buf[t&1] ---
    const char* xb = XlB + (t & 1) * 32768;
    #pragma unroll
    for (int ks = 0; ks < T::ksc[t]; ++ks) {
      bf16x8 af[4];
      #pragma unroll
      for (int mi = 0; mi < 4; ++mi) {
        int row = mh + mi * 16 + l15;
        int sz = (row & 7) << 4;
        const char* rb = xb + row * 256;
        if (T::tf32[t]) {
          int cb = ks * 128 + quad * 32;
          float4 f0 = *(const float4*)(rb + (cb ^ sz));
          float4 f1 = *(const float4*)(rb + ((cb + 16) ^ sz));
          union { ushort us[8]; bf16x8 v; } cv;
          cv.us[0] = f2bf(f0.x); cv.us[1] = f2bf(f0.y);
          cv.us[2] = f2bf(f0.z); cv.us[3] = f2bf(f0.w);
          cv.us[4] = f2bf(f1.x); cv.us[5] = f2bf(f1.y);
          cv.us[6] = f2bf(f1.z); cv.us[7] = f2bf(f1.w);
          af[mi] = cv.v;
        } else {
          int cb = ks * 64 + quad * 16;
          af[mi] = *(const bf16x8*)(rb + (cb ^ sz));
        }
      }
      #pragma unroll
      for (int mi = 0; mi < 4; ++mi)
        #pragma unroll
        for (int ni = 0; ni < 2; ++ni)
          acc[mi][ni] = __builtin_amdgcn_mfma_f32_16x16x32_bf16(
              af[mi], bq[ks * 2 + ni], acc[mi][ni], 0, 0, 0);
    }
    __syncthreads();  // drains stage(t+1) (vmcnt(0) auto) + buffer handoff
  }
}

// ---------------- fused edge MLP: pipelined gather + GEMM(MFMA) + relu + dot(W2) ----------------
__global__ __launch_bounds__(512, 4) void edge_kernel(
    const void* __restrict__ hv, const ushort* __restrict__ hbf, int preconv,
    const int* __restrict__ ei, const void* __restrict__ eav,
    const int* __restrict__ batch, const ushort* __restrict__ pooled,
    const ushort* __restrict__ Wfrag, const void* __restrict__ b1v,
    const void* __restrict__ W2v, const void* __restrict__ b2v,
    void* __restrict__ outv, int E) {
  __shared__ __align__(16) char XlB[2 * 32768];  // X double buffer, linear 256B rows
  __shared__ int rs[TM], rt[TM], rg[TM];
  __shared__ float outacc[TM];
  __shared__ float b1s[kH], w2s[kH];
  lds_char* Xl3 = (lds_char*)XlB;  // AS(3) view, derived at the declaration

  const int tid = threadIdx.x;
  const int e0 = blockIdx.x * TM;
  const bool isf32 = data_is_f32(hv);
  const bool is64 = idx_is_64(ei);

  if (tid < TM) {
    int e = e0 + tid; if (e >= E) e = E - 1;
    int s = is64 ? ei[2 * e] : ei[e];
    int t = is64 ? ei[2 * (E + e)] : ei[E + e];
    rs[tid] = s;
    rt[tid] = t;
    rg[tid] = is64 ? batch[2 * s] : batch[s];
    w2s[tid] = loadf(W2v, tid, isf32);
    b1s[tid] = loadf(b1v, tid, isf32);
    outacc[tid] = 0.f;
  }
  __syncthreads();

  const int wave = tid >> 6, lane = tid & 63;
  const int l15 = lane & 15, quad = lane >> 4;
  const int mh = (wave & 1) * 64;
  const int nq = wave >> 1;
  const int nhi = nq >> 1;
  const int nlo = (nq & 1) * 2;

  f32x4 acc[4][2];
  #pragma unroll
  for (int i = 0; i < 4; ++i)
    #pragma unroll
    for (int j = 0; j < 2; ++j)
      acc[i][j] = (f32x4){0.f, 0.f, 0.f, 0.f};

  const bool hb = !isf32 || preconv;
  const char* hsrc = !isf32 ? (const char*)hv
                            : (preconv ? (const char*)hbf : (const char*)hv);
  const bool ea32 = data_is_f32(eav);

  if (hb) {
    if (ea32) edge_core<true, true >((const char*)hsrc, (const char*)eav, pooled,
                                     Wfrag, XlB, Xl3, rs, rt, rg, e0, E, wave, lane, acc);
    else      edge_core<true, false>((const char*)hsrc, (const char*)eav, pooled,
                                     Wfrag, XlB, Xl3, rs, rt, rg, e0, E, wave, lane, acc);
  } else {
    if (ea32) edge_core<false, true >((const char*)hsrc, (const char*)eav, pooled,
                                      Wfrag, XlB, Xl3, rs, rt, rg, e0, E, wave, lane, acc);
    else      edge_core<false, false>((const char*)hsrc, (const char*)eav, pooled,
                                      Wfrag, XlB, Xl3, rs, rt, rg, e0, E, wave, lane, acc);
  }

  // ---- epilogue: sum_n relu(hid + b1) * W2 via shfl over the 16 n-lanes ----
  // C/D layout: col n = lane&15, row m = quad*4 + reg
  float w2v[2], b1r[2];
  #pragma unroll
  for (int ni = 0; ni < 2; ++ni) {
    int n = nhi * 64 + (nlo + ni) * 16 + l15;
    w2v[ni] = w2s[n];
    b1r[ni] = b1s[n];
  }
  #pragma unroll
  for (int mi = 0; mi < 4; ++mi) {
    float ps[4] = {0.f, 0.f, 0.f, 0.f};
    #pragma unroll
    for (int ni = 0; ni < 2; ++ni)
      #pragma unroll
      for (int j = 0; j < 4; ++j) {
        float v = acc[mi][ni][j] + b1r[ni];
        ps[j] += (v > 0.f ? v : 0.f) * w2v[ni];
      }
    #pragma unroll
    for (int off = 1; off < 16; off <<= 1)
      #pragma unroll
      for (int j = 0; j < 4; ++j)
        ps[j] += __shfl_xor(ps[j], off, 64);
    if (l15 == 0)
      #pragma unroll
      for (int j = 0; j < 4; ++j)
        atomicAdd(&outacc[mh + mi * 16 + quad * 4 + j], ps[j]);
  }
  __syncthreads();
  if (tid < TM) {
    int e = e0 + tid;
    if (e < E) {
      float a = outacc[tid] + loadf(b2v, 0, isf32);
      if (isf32) ((float*)outv)[e] = a;
      else       ((ushort*)outv)[e] = f2bf(a);
    }
  }
}

extern "C" void kernel_launch(void* const* d_in, const int* in_sizes, int n_in,
                              void* d_out, int out_size, void* d_ws, size_t ws_size,
                              hipStream_t stream) {
  const void* h   = d_in[0];
  const int*  ei  = (const int*)d_in[1];
  const void* ea  = d_in[2];
  const int*  bat = (const int*)d_in[3];
  const void* W1  = d_in[4];
  const void* b1  = d_in[5];
  const void* W2  = d_in[6];
  const void* b2  = d_in[7];

  const int N = in_sizes[3];
  const int E = in_sizes[1] / 2;

  // ws layout: pooled bf16 [2048][256] | Wfrag bf16 [224*64*8] | hbf bf16 [N][256]
  ushort* pooled = (ushort*)d_ws;
  ushort* Wfrag  = pooled + (size_t)kB * kND;
  ushort* hbf    = Wfrag + (size_t)kNF * 512;
  const size_t need =
      ((size_t)kB * kND + (size_t)kNF * 512 + (size_t)N * kND) * sizeof(ushort);
  const int preconv = (ws_size >= need) ? 1 : 0;

  pool_kernel<<<kB, 256, 0, stream>>>(h, hbf, preconv, bat, ei, N, pooled);
  build_wfrag<<<(kNF * 64 + 255) / 256, 256, 0, stream>>>(W1, Wfrag);
  edge_kernel<<<(E + TM - 1) / TM, 512, 0, stream>>>(
      h, hbf, preconv, ei, ea, bat, pooled, Wfrag, b1, W2, b2, d_out, E);
}